// Round 7
// baseline (678.880 us; speedup 1.0000x reference)
//
#include <hip/hip_runtime.h>

// SNN forward targeting bit-match with JAX XLA:CPU fp32 reference:
//  - einsum [51200,784]x[784,128]: Eigen ThreadPool contraction semantics:
//      kc=320 panel blocking -> per element C = ((chain(0:320)+chain(320:640))
//      + chain(640:784)), each chain sequential-d, single acc, separate
//      mul/add rounding (AVX-baseline Eigen, no FMA); then +b1 separately.
//  - LIF scan fp32, LLVM-contracted form: mem = fma(0.95,mem,cur) - reset
//  - layer 2 (spk1 @ W2.T): spk in {0,1} => products exact; sequential-k
//      single-accumulator sum h=0..127, then separate +b2.
// B=512, T=100, D=784, H=128, O=10. Fused, one block per batch element.

#define T_STEPS 100
#define TC      50
#define B_SZ    512
#define D_IN    784
#define H_SZ    128
#define O_SZ    10
#define NCHUNK  49   // 784 / 16

__global__ __launch_bounds__(256) void snn_xla_kernel(
    const float* __restrict__ x,   // [B, T, D]
    const float* __restrict__ W1,  // [H, D]
    const float* __restrict__ b1,  // [H]
    const float* __restrict__ W2,  // [O, H]
    const float* __restrict__ b2,  // [O]
    float* __restrict__ out) {     // spk2 [T*B*O] then mem2 [T*B*O]

  __shared__ float xs[64 * 17];      // x tile  [64 t-slots][16 d], stride 17
  __shared__ float ws1[H_SZ * 17];   // W1 tile [128 h][16 d], stride 17
  __shared__ float cur1[TC * 130];   // currents for this t-chunk
  __shared__ float w2s[O_SZ * 132];  // W2 staged
  __shared__ float spks[H_SZ];       // layer-1 spikes this step

  const int tid = threadIdx.x;
  const int b = blockIdx.x;
  const int tx = tid & 15;           // h-lane: h = tx + 16*j
  const int ty = tid >> 4;           // t-lane: t = ty + 16*i

  for (int i = tid; i < O_SZ * H_SZ; i += 256)
    w2s[(i >> 7) * 132 + (i & 127)] = W2[i];
  const float b2v = (tid < O_SZ) ? b2[tid] : 0.f;

  float mem1 = 0.f, mem2 = 0.f;      // persistent fp32 scan state
  __syncthreads();

  const float* xb = x + (size_t)b * T_STEPS * D_IN;

  for (int ch = 0; ch < 2; ++ch) {
    const int t0 = ch * TC;

    // ---- phase 1: einsum with Eigen kc=320 panel semantics ----
    float tot[4][8], pc[4][8];
#pragma unroll
    for (int i = 0; i < 4; ++i)
#pragma unroll
      for (int j = 0; j < 8; ++j) { tot[i][j] = 0.f; pc[i][j] = 0.f; }

    for (int c = 0; c < NCHUNK; ++c) {
      const int k0 = c * 16;
      if (c == 20 || c == 40) {      // panel boundary at d=320, d=640
#pragma unroll
        for (int i = 0; i < 4; ++i)
#pragma unroll
          for (int j = 0; j < 8; ++j) {
            tot[i][j] = __fadd_rn(tot[i][j], pc[i][j]);
            pc[i][j] = 0.f;
          }
      }
      __syncthreads();               // previous chunk readers done
      {
        const int r = tid >> 2;              // 0..63
        const int c4 = (tid & 3) * 4;        // 0,4,8,12
        float4 v = make_float4(0.f, 0.f, 0.f, 0.f);
        if (r < TC)
          v = *reinterpret_cast<const float4*>(
              &xb[(size_t)(t0 + r) * D_IN + k0 + c4]);
        xs[r * 17 + c4 + 0] = v.x;
        xs[r * 17 + c4 + 1] = v.y;
        xs[r * 17 + c4 + 2] = v.z;
        xs[r * 17 + c4 + 3] = v.w;
#pragma unroll
        for (int it = 0; it < 2; ++it) {
          const int wr = r + 64 * it;        // 0..127
          const float4 w = *reinterpret_cast<const float4*>(
              &W1[(size_t)wr * D_IN + k0 + c4]);
          ws1[wr * 17 + c4 + 0] = w.x;
          ws1[wr * 17 + c4 + 1] = w.y;
          ws1[wr * 17 + c4 + 2] = w.z;
          ws1[wr * 17 + c4 + 3] = w.w;
        }
      }
      __syncthreads();
#pragma unroll
      for (int kk = 0; kk < 16; ++kk) {      // d ascending within chunk
        float a[4], bb[8];
#pragma unroll
        for (int i = 0; i < 4; ++i) a[i] = xs[(ty + 16 * i) * 17 + kk];
#pragma unroll
        for (int j = 0; j < 8; ++j) bb[j] = ws1[(tx + 16 * j) * 17 + kk];
#pragma unroll
        for (int i = 0; i < 4; ++i)
#pragma unroll
          for (int j = 0; j < 8; ++j)
            pc[i][j] = __fadd_rn(pc[i][j], __fmul_rn(a[i], bb[j]));
      }
    }
    __syncthreads();

    // final panel fold + b1, write cur1
#pragma unroll
    for (int i = 0; i < 4; ++i) {
      const int t = ty + 16 * i;
      if (t < TC) {
#pragma unroll
        for (int j = 0; j < 8; ++j) {
          const int h = tx + 16 * j;
          const float v = __fadd_rn(tot[i][j], pc[i][j]);
          cur1[t * 130 + h] = __fadd_rn(v, b1[h]);
        }
      }
    }
    __syncthreads();

    // ---- phase 2: fp32 LIF scan (FMA-contracted form) ----
    for (int tc = 0; tc < TC; ++tc) {
      if (tid < H_SZ) {
        const float cur = cur1[tc * 130 + tid];
        const float reset1 = (mem1 > 1.f) ? 1.f : 0.f;
        mem1 = __fsub_rn(fmaf(0.95f, mem1, cur), reset1);
        spks[tid] = (mem1 > 1.f) ? 1.f : 0.f;
      }
      __syncthreads();
      if (tid < O_SZ) {
        // sequential-k sum; spk in {0,1} makes every product exact
        float a = 0.f;
#pragma unroll 16
        for (int k = 0; k < H_SZ; ++k)
          a = fmaf(spks[k], w2s[tid * 132 + k], a);
        const float cur2 = __fadd_rn(a, b2v);
        const float reset2 = (mem2 > 1.f) ? 1.f : 0.f;
        mem2 = __fsub_rn(fmaf(0.95f, mem2, cur2), reset2);
        const float spk2 = (mem2 > 1.f) ? 1.f : 0.f;
        const size_t idx = ((size_t)(t0 + tc) * B_SZ + b) * O_SZ + tid;
        out[idx] = spk2;
        out[(size_t)T_STEPS * B_SZ * O_SZ + idx] = mem2;
      }
      __syncthreads();
    }
  }
}

extern "C" void kernel_launch(void* const* d_in, const int* in_sizes, int n_in,
                              void* d_out, int out_size, void* d_ws, size_t ws_size,
                              hipStream_t stream) {
  const float* x  = (const float*)d_in[0];   // [512,100,784]
  const float* W1 = (const float*)d_in[1];   // [128,784]
  const float* b1 = (const float*)d_in[2];   // [128]
  const float* W2 = (const float*)d_in[3];   // [10,128]
  const float* b2 = (const float*)d_in[4];   // [10]
  float* out = (float*)d_out;

  snn_xla_kernel<<<dim3(B_SZ), dim3(256), 0, stream>>>(
      x, W1, b1, W2, b2, out);
}